// Round 1
// 1387.918 us; speedup vs baseline: 1.2067x; 1.2067x over previous
//
#include <hip/hip_runtime.h>

// Problem constants (from reference)
constexpr int PT_  = 500000;  // total params
constexpr int KT_  = 398;     // total bases
constexpr int KTP_ = 400;     // padded E row stride (16B-aligned rows)

// ws layout (floats):
//   E    [64*400]  @ 0       (zeroed; atomically accumulated)
//   NG   [64]      @ 25600   (||G[b]||^2, atomic)
//   NA   [64]      @ 25664   (||approx[b]||^2, atomic)
//   w    [398]     @ 25728
//   sRes [64]      @ 26126

__global__ __launch_bounds__(256) void zero_kernel(float* __restrict__ p, int n) {
    int i = blockIdx.x * 256 + threadIdx.x;
    if (i < n) p[i] = 0.f;
}

// ---------------- Pass A body: E = G @ B (split-K partials via atomics) + ||G[b]||^2 ----------------
// Inlined per-group with shared LDS passed in (single allocation in the merged kernel).
template <int KG, int KSLOT, int CP>
__device__ __forceinline__ void kernelA_body(const float* __restrict__ G,
                                             const float* __restrict__ Bg,
                                             int Pg, int poff, int koff,
                                             float* __restrict__ E,
                                             float* __restrict__ NG,
                                             int bid,
                                             float* __restrict__ Gst,   // [32*68]  [j][b] stride 68
                                             float* __restrict__ Bs) {  // [32*KG]  [j][k] flat
    const int t  = threadIdx.x;
    const int q  = t >> 6;   // b-quarter (wave-uniform -> Gst b128 reads broadcast)
    const int kk = t & 63;

    float acc[16][KSLOT];
#pragma unroll
    for (int i = 0; i < 16; i++)
#pragma unroll
        for (int m = 0; m < KSLOT; m++) acc[i][m] = 0.f;

    int kidx[KSLOT];
#pragma unroll
    for (int m = 0; m < KSLOT; m++) {
        int k   = kk + 64 * m;
        kidx[m] = (k < KG) ? k : (KG - 1);   // clamp: OOB lanes read last valid col (broadcast)
    }

    float ng[8];
#pragma unroll
    for (int r = 0; r < 8; r++) ng[r] = 0.f;

    const int p0 = bid * CP;

    for (int jj = 0; jj < CP; jj += 32) {
        __syncthreads();
#pragma unroll
        for (int r = 0; r < 8; r++) {
            int   idx = t + 256 * r;       // j = t&31 fixed, b = (t>>5)+8r
            int   b   = idx >> 5, j = idx & 31;
            int   p   = p0 + jj + j;
            float v   = (p < Pg) ? G[(size_t)b * PT_ + poff + p] : 0.f;
            Gst[j * 68 + b] = v;
            ng[r] += v * v;
        }
        for (int idx = t; idx < 32 * KG; idx += 256) {
            int j = idx / KG, c = idx - j * KG;
            int p = p0 + jj + j;
            Bs[idx] = (p < Pg) ? Bg[(size_t)p * KG + c] : 0.f;
        }
        __syncthreads();
#pragma unroll 2
        for (int j = 0; j < 32; j++) {
            float bv[KSLOT];
#pragma unroll
            for (int m = 0; m < KSLOT; m++) bv[m] = Bs[j * KG + kidx[m]];
            const float4* gp = reinterpret_cast<const float4*>(&Gst[j * 68 + 16 * q]);
            float4 ga = gp[0], gb = gp[1], gc = gp[2], gd = gp[3];
            float  g[16] = {ga.x, ga.y, ga.z, ga.w, gb.x, gb.y, gb.z, gb.w,
                            gc.x, gc.y, gc.z, gc.w, gd.x, gd.y, gd.z, gd.w};
#pragma unroll
            for (int i = 0; i < 16; i++)
#pragma unroll
                for (int m = 0; m < KSLOT; m++) acc[i][m] += g[i] * bv[m];
        }
    }

#pragma unroll
    for (int i = 0; i < 16; i++) {
        int b = 16 * q + i;
#pragma unroll
        for (int m = 0; m < KSLOT; m++) {
            int k = kk + 64 * m;
            if (k < KG) atomicAdd(&E[b * KTP_ + koff + k], acc[i][m]);
        }
    }

    __syncthreads();
    if (t < 64) Gst[t] = 0.f;
    __syncthreads();
#pragma unroll
    for (int r = 0; r < 8; r++) atomicAdd(&Gst[(t >> 5) + 8 * r], ng[r]);
    __syncthreads();
    if (t < 64) atomicAdd(&NG[t], Gst[t]);
}

// Merged pass A: all three groups in ONE dispatch so blocks co-schedule across the chip.
// CP=384 -> 261+586+456 = 1303 blocks ~= 5.1/CU, saturating the 5-block LDS cap (28672 B).
constexpr int CPA   = 384;
constexpr int NBA0  = (100000 + CPA - 1) / CPA;  // 261
constexpr int NBA1  = (225000 + CPA - 1) / CPA;  // 586
constexpr int NBA2  = (175000 + CPA - 1) / CPA;  // 456

__global__ __launch_bounds__(256) void kernelA_all(const float* __restrict__ G,
                                                   const float* __restrict__ B0,
                                                   const float* __restrict__ B1,
                                                   const float* __restrict__ B2,
                                                   float* __restrict__ E,
                                                   float* __restrict__ NG) {
    __shared__ float smem[32 * 68 + 32 * 156];   // 28672 B (max over groups)
    float* Gst = smem;
    float* Bs  = smem + 32 * 68;
    const int bx = blockIdx.x;
    if (bx < NBA0) {
        kernelA_body<104, 2, CPA>(G, B0, 100000, 0,      0,   E, NG, bx, Gst, Bs);
    } else if (bx < NBA0 + NBA1) {
        kernelA_body<156, 3, CPA>(G, B1, 225000, 100000, 104, E, NG, bx - NBA0, Gst, Bs);
    } else {
        kernelA_body<138, 3, CPA>(G, B2, 175000, 325000, 260, E, NG, bx - NBA0 - NBA1, Gst, Bs);
    }
}

// ---------------- Kernel B: ||approx[b]||^2 via on-the-fly (E @ B^T) row-square-sum ----------------
template <int KG, int SB>
__global__ __launch_bounds__(256) void kernelB(const float* __restrict__ Bg,
                                               const float* __restrict__ E,
                                               int Pg, int koff, int nTiles,
                                               float* __restrict__ NA) {
    __shared__ float Bs[64 * SB];
    __shared__ float red[64];
    const int t  = threadIdx.x;
    const int q  = t >> 5;   // b-octet 0..7
    const int pp = t & 31;

    float pn[8];
#pragma unroll
    for (int i = 0; i < 8; i++) pn[i] = 0.f;

    const float* Erow = E + (8 * q) * KTP_ + koff;

    for (int tile = blockIdx.x; tile < nTiles; tile += gridDim.x) {
        const int p0 = tile * 64;
        __syncthreads();
        for (int idx = t; idx < 64 * SB; idx += 256) {
            int r = idx / SB, c = idx - r * SB;
            int p = p0 + r;
            Bs[idx] = (c < KG && p < Pg) ? Bg[(size_t)p * KG + c] : 0.f;
        }
        __syncthreads();
        float c0[8], c1[8];
#pragma unroll
        for (int i = 0; i < 8; i++) { c0[i] = 0.f; c1[i] = 0.f; }
        for (int k = 0; k < SB; k += 4) {
            float4 bv0 = *reinterpret_cast<const float4*>(&Bs[pp * SB + k]);
            float4 bv1 = *reinterpret_cast<const float4*>(&Bs[(pp + 32) * SB + k]);
#pragma unroll
            for (int i = 0; i < 8; i++) {
                float4 ev = *reinterpret_cast<const float4*>(&Erow[i * KTP_ + k]);
                c0[i] += ev.x * bv0.x + ev.y * bv0.y + ev.z * bv0.z + ev.w * bv0.w;
                c1[i] += ev.x * bv1.x + ev.y * bv1.y + ev.z * bv1.z + ev.w * bv1.w;
            }
        }
#pragma unroll
        for (int i = 0; i < 8; i++) pn[i] += c0[i] * c0[i] + c1[i] * c1[i];
    }

    __syncthreads();
    if (t < 64) red[t] = 0.f;
    __syncthreads();
#pragma unroll
    for (int i = 0; i < 8; i++) atomicAdd(&red[8 * q + i], pn[i]);
    __syncthreads();
    if (t < 64) atomicAdd(&NA[t], red[t]);
}

// ---------------- Kernel C: scales, out0 (avg clipped embedding), w ----------------
__global__ __launch_bounds__(256) void kernelC(const float* __restrict__ NG,
                                               const float* __restrict__ NA,
                                               const float* __restrict__ E,
                                               float* __restrict__ w, float* __restrict__ sRes,
                                               float* __restrict__ out0) {
    __shared__ float red[256];
    __shared__ float sEmb[64], sResS[64];
    const int t = threadIdx.x;
    const int b = t & 63, part = t >> 6;

    float acc = 0.f;
    for (int k = part * 100; k < part * 100 + 100; k++) {  // pad cols 398/399 are 0
        float v = E[b * KTP_ + k];
        acc += v * v;
    }
    red[part * 64 + b] = acc;
    __syncthreads();
    if (t < 64) {
        float ne   = red[t] + red[64 + t] + red[128 + t] + red[192 + t];
        float nrm  = sqrtf(fmaxf(ne, 0.f));
        sEmb[t]    = fminf(1.0f / nrm, 1.0f);   // CLIP0 = 1
        // <G[b], approx[b]> == ||E[b]||^2 exactly (E = G B):
        float rn2  = NG[t] - 2.f * ne + NA[t];
        float rnrm = sqrtf(fmaxf(rn2, 0.f));
        float sv   = fminf(1.0f / rnrm, 1.0f);  // CLIP1 = 1
        sResS[t]   = sv;
        sRes[t]    = sv;
    }
    __syncthreads();

    for (int k = t; k < KT_; k += 256) {
        float e0 = 0.f, wv = 0.f;
        for (int bb = 0; bb < 64; bb++) {
            float v = E[bb * KTP_ + k];
            e0 += sEmb[bb] * v;
            wv += sResS[bb] * v;
        }
        out0[k] = e0 * (1.f / 64.f);
        w[k]    = wv;
    }
}

// ---------------- Kernel D: out1 = (sum_b s_b G[b,p] - sum_k w[k] B[p,k])/64 ; out2 = mean_b G ----------------
// Block handles 64 p-columns; B tile staged in LDS (coalesced); 4 threads cooperate per p.
template <int KG>
__global__ __launch_bounds__(256) void kernelD(const float* __restrict__ G,
                                               const float* __restrict__ Bg,
                                               const float* __restrict__ w,
                                               const float* __restrict__ sRes,
                                               int Pg, int poff, int koff,
                                               float* __restrict__ out1, float* __restrict__ out2) {
    constexpr int LDB = KG + 1;           // odd stride -> conflict-free column reads
    constexpr int KQ  = (KG + 3) / 4;     // k-chunk per part
    __shared__ float Bt[64 * LDB];
    __shared__ float wS[KG];
    __shared__ float sS[64];
    __shared__ float redA[256], redT[256], redD[256];
    const int t    = threadIdx.x;
    const int pidx = t & 63, part = t >> 6;
    const int p0   = blockIdx.x * 64;

    for (int k = t; k < KG; k += 256) wS[k] = w[koff + k];
    if (t < 64) sS[t] = sRes[t];
    for (int idx = t; idx < 64 * KG; idx += 256) {
        int r = idx / KG, c = idx - r * KG;
        int p = p0 + r;
        Bt[r * LDB + c] = (p < Pg) ? Bg[(size_t)p * KG + c] : 0.f;
    }
    __syncthreads();

    const int p = p0 + pidx;
    float a = 0.f, t2 = 0.f, dot = 0.f;
    if (p < Pg) {
#pragma unroll
        for (int bi = 0; bi < 16; bi++) {
            int   b = part * 16 + bi;
            float g = G[(size_t)b * PT_ + poff + p];
            a  += sS[b] * g;
            t2 += g;
        }
        const int k1 = (part * KQ + KQ < KG) ? (part * KQ + KQ) : KG;
        for (int k = part * KQ; k < k1; k++) dot += wS[k] * Bt[pidx * LDB + k];
    }
    redA[t] = a; redT[t] = t2; redD[t] = dot;
    __syncthreads();
    if (part == 0 && p < Pg) {
        float A = redA[t] + redA[64 + t] + redA[128 + t] + redA[192 + t];
        float T = redT[t] + redT[64 + t] + redT[128 + t] + redT[192 + t];
        float D = redD[t] + redD[64 + t] + redD[128 + t] + redD[192 + t];
        out1[poff + p] = (A - D) * (1.f / 64.f);
        out2[poff + p] = T * (1.f / 64.f);
    }
}

extern "C" void kernel_launch(void* const* d_in, const int* in_sizes, int n_in,
                              void* d_out, int out_size, void* d_ws, size_t ws_size,
                              hipStream_t stream) {
    const float* G  = (const float*)d_in[0];
    const float* B0 = (const float*)d_in[1];
    const float* B1 = (const float*)d_in[2];
    const float* B2 = (const float*)d_in[3];
    float* out  = (float*)d_out;
    float* out0 = out;                  // [398]
    float* out1 = out + KT_;            // [500000]
    float* out2 = out + KT_ + PT_;      // [500000]

    float* ws = (float*)d_ws;
    float* E  = ws;                     // 25600
    float* NG = ws + 25600;             // 64
    float* NA = NG + 64;                // 64
    float* w  = NA + 64;                // 398
    float* sR = w + KT_;                // 64

    // zero E + NG + NA (ws is poisoned 0xAA before every timed launch)
    zero_kernel<<<101, 256, 0, stream>>>(E, 25728);

    // Pass A (merged): embeddings + ||G[b]||^2 — 1303 blocks ~= 5.1/CU (LDS cap 5)
    kernelA_all<<<NBA0 + NBA1 + NBA2, 256, 0, stream>>>(G, B0, B1, B2, E, NG);

    // Pass B: ||approx[b]||^2 — 1024 blocks = 4/CU at 40 KB LDS
    kernelB<104, 108><<<1024, 256, 0, stream>>>(B0, E, 100000, 0,   (100000 + 63) / 64, NA);
    kernelB<156, 156><<<1024, 256, 0, stream>>>(B1, E, 225000, 104, (225000 + 63) / 64, NA);
    kernelB<138, 140><<<1024, 256, 0, stream>>>(B2, E, 175000, 260, (175000 + 63) / 64, NA);

    // Pass C: scales + avg clipped embedding + w
    kernelC<<<1, 256, 0, stream>>>(NG, NA, E, w, sR, out0);

    // Pass D: avg clipped residual + avg target grad (64 p per block, LDS-staged B)
    kernelD<104><<<(100000 + 63) / 64, 256, 0, stream>>>(G, B0, w, sR, 100000, 0,      0,   out1, out2);
    kernelD<156><<<(225000 + 63) / 64, 256, 0, stream>>>(G, B1, w, sR, 225000, 100000, 104, out1, out2);
    kernelD<138><<<(175000 + 63) / 64, 256, 0, stream>>>(G, B2, w, sR, 175000, 325000, 260, out1, out2);
}

// Round 2
// 1169.731 us; speedup vs baseline: 1.4318x; 1.1865x over previous
//
#include <hip/hip_runtime.h>

// Problem constants (from reference)
constexpr int PT_  = 500000;  // total params
constexpr int KT_  = 398;     // total bases
constexpr int KTP_ = 400;     // padded E row stride (16B-aligned rows)

// ws layout (floats):
//   E    [64*400]  @ 0       (zeroed; atomically accumulated)
//   NG   [64]      @ 25600   (||G[b]||^2, atomic)
//   NA   [64]      @ 25664   (||approx[b]||^2, atomic)
//   w    [398]     @ 25728
//   sRes [64]      @ 26126

__global__ __launch_bounds__(256) void zero_kernel(float* __restrict__ p, int n) {
    int i = blockIdx.x * 256 + threadIdx.x;
    if (i < n) p[i] = 0.f;
}

// ---------------- Pass A: E = G @ B (split-K partials via atomics) + ||G[b]||^2 ----------------
// v2: B read DIRECTLY from global (coalesced, L1-cached 4x reuse across q-waves).
// LDS = Gst only (8.7 KB) -> >=5 blocks/CU under any LDS budget.
template <int KG, int KSLOT, int CP>
__device__ __forceinline__ void kernelA_body(const float* __restrict__ G,
                                             const float* __restrict__ Bg,
                                             int Pg, int poff, int koff,
                                             float* __restrict__ E,
                                             float* __restrict__ NG,
                                             int bid,
                                             float* __restrict__ Gst) {  // [32*68] [j][b]
    const int t  = threadIdx.x;
    const int q  = t >> 6;   // b-quarter (wave-uniform -> Gst b128 reads broadcast)
    const int kk = t & 63;

    float acc[16][KSLOT];
#pragma unroll
    for (int i = 0; i < 16; i++)
#pragma unroll
        for (int m = 0; m < KSLOT; m++) acc[i][m] = 0.f;

    int kidx[KSLOT];
#pragma unroll
    for (int m = 0; m < KSLOT; m++) {
        int k   = kk + 64 * m;
        kidx[m] = (k < KG) ? k : (KG - 1);   // clamp: OOB lanes re-read last col (harmless)
    }

    float ng[8];
#pragma unroll
    for (int r = 0; r < 8; r++) ng[r] = 0.f;

    const int p0 = bid * CP;

    for (int jj = 0; jj < CP; jj += 32) {
        __syncthreads();
#pragma unroll
        for (int r = 0; r < 8; r++) {
            int   idx = t + 256 * r;       // j = idx&31, b = idx>>5
            int   b   = idx >> 5, j = idx & 31;
            int   p   = p0 + jj + j;
            float v   = (p < Pg) ? G[(size_t)b * PT_ + poff + p] : 0.f;
            Gst[j * 68 + b] = v;
            ng[r] += v * v;
        }
        __syncthreads();

        int rem  = Pg - (p0 + jj);
        int jmax = rem < 32 ? (rem < 0 ? 0 : rem) : 32;   // wave-uniform bound
#pragma unroll 2
        for (int j = 0; j < jmax; j++) {
            const float* Brow = Bg + (size_t)(p0 + jj + j) * KG;
            float bv[KSLOT];
#pragma unroll
            for (int m = 0; m < KSLOT; m++) bv[m] = Brow[kidx[m]];   // coalesced global, L1-hot
            const float4* gp = reinterpret_cast<const float4*>(&Gst[j * 68 + 16 * q]);
            float4 ga = gp[0], gb = gp[1], gc = gp[2], gd = gp[3];
#pragma unroll
            for (int m = 0; m < KSLOT; m++) {
                float b0 = bv[m];
                acc[0][m]  += ga.x * b0; acc[1][m]  += ga.y * b0;
                acc[2][m]  += ga.z * b0; acc[3][m]  += ga.w * b0;
                acc[4][m]  += gb.x * b0; acc[5][m]  += gb.y * b0;
                acc[6][m]  += gb.z * b0; acc[7][m]  += gb.w * b0;
                acc[8][m]  += gc.x * b0; acc[9][m]  += gc.y * b0;
                acc[10][m] += gc.z * b0; acc[11][m] += gc.w * b0;
                acc[12][m] += gd.x * b0; acc[13][m] += gd.y * b0;
                acc[14][m] += gd.z * b0; acc[15][m] += gd.w * b0;
            }
        }
    }

#pragma unroll
    for (int i = 0; i < 16; i++) {
        int b = 16 * q + i;
#pragma unroll
        for (int m = 0; m < KSLOT; m++) {
            int k = kk + 64 * m;
            if (k < KG) atomicAdd(&E[b * KTP_ + koff + k], acc[i][m]);
        }
    }

    __syncthreads();
    if (t < 64) Gst[t] = 0.f;
    __syncthreads();
#pragma unroll
    for (int r = 0; r < 8; r++) atomicAdd(&Gst[(t >> 5) + 8 * r], ng[r]);
    __syncthreads();
    if (t < 64) atomicAdd(&NG[t], Gst[t]);
}

constexpr int CPA  = 384;
constexpr int NBA0 = (100000 + CPA - 1) / CPA;  // 261
constexpr int NBA1 = (225000 + CPA - 1) / CPA;  // 586
constexpr int NBA2 = (175000 + CPA - 1) / CPA;  // 456

__global__ __launch_bounds__(256) void kernelA_all(const float* __restrict__ G,
                                                   const float* __restrict__ B0,
                                                   const float* __restrict__ B1,
                                                   const float* __restrict__ B2,
                                                   float* __restrict__ E,
                                                   float* __restrict__ NG) {
    __shared__ __align__(16) float Gst[32 * 68];   // 8704 B
    const int bx = blockIdx.x;
    if (bx < NBA0) {
        kernelA_body<104, 2, CPA>(G, B0, 100000, 0,      0,   E, NG, bx, Gst);
    } else if (bx < NBA0 + NBA1) {
        kernelA_body<156, 3, CPA>(G, B1, 225000, 100000, 104, E, NG, bx - NBA0, Gst);
    } else {
        kernelA_body<138, 3, CPA>(G, B2, 175000, 325000, 260, E, NG, bx - NBA0 - NBA1, Gst);
    }
}

// ---------------- Pass B: ||approx[b]||^2 via on-the-fly (E @ B^T) row-square-sum ----------------
// v2: 128-p x 52-k chunked LDS tile (26.9 KB), 4 p-rows/thread, one tile per block, merged groups.
template <int KG>
__device__ __forceinline__ void kernelB_body(const float* __restrict__ Bg,
                                             const float* __restrict__ E,
                                             int Pg, int koff, int tile,
                                             float* __restrict__ Bs,    // [128*52]
                                             float* __restrict__ red,   // [64]
                                             float* __restrict__ NA) {
    const int t  = threadIdx.x;
    const int q  = t >> 5;   // b-octet 0..7
    const int pp = t & 31;
    constexpr int NC = (KG + 51) / 52;
    const int p0 = tile * 128;

    float c[4][8];
#pragma unroll
    for (int r = 0; r < 4; r++)
#pragma unroll
        for (int i = 0; i < 8; i++) c[r][i] = 0.f;

    for (int ch = 0; ch < NC; ch++) {
        const int c0 = ch * 52;
        __syncthreads();
        for (int idx = t; idx < 128 * 52; idx += 256) {
            int r = idx / 52, cc = idx - 52 * r;
            int p = p0 + r, k = c0 + cc;
            Bs[idx] = (p < Pg && k < KG) ? Bg[(size_t)p * KG + k] : 0.f;
        }
        __syncthreads();
        const float* Eb = E + koff + c0;
        for (int k4 = 0; k4 < 52; k4 += 4) {
            float4 bv0 = *reinterpret_cast<const float4*>(&Bs[(pp      ) * 52 + k4]);
            float4 bv1 = *reinterpret_cast<const float4*>(&Bs[(pp + 32 ) * 52 + k4]);
            float4 bv2 = *reinterpret_cast<const float4*>(&Bs[(pp + 64 ) * 52 + k4]);
            float4 bv3 = *reinterpret_cast<const float4*>(&Bs[(pp + 96 ) * 52 + k4]);
#pragma unroll
            for (int i = 0; i < 8; i++) {
                float4 ev = *reinterpret_cast<const float4*>(&Eb[(8 * q + i) * KTP_ + k4]);
                c[0][i] += ev.x * bv0.x + ev.y * bv0.y + ev.z * bv0.z + ev.w * bv0.w;
                c[1][i] += ev.x * bv1.x + ev.y * bv1.y + ev.z * bv1.z + ev.w * bv1.w;
                c[2][i] += ev.x * bv2.x + ev.y * bv2.y + ev.z * bv2.z + ev.w * bv2.w;
                c[3][i] += ev.x * bv3.x + ev.y * bv3.y + ev.z * bv3.z + ev.w * bv3.w;
            }
        }
    }

    float na[8];
#pragma unroll
    for (int i = 0; i < 8; i++)
        na[i] = c[0][i] * c[0][i] + c[1][i] * c[1][i] + c[2][i] * c[2][i] + c[3][i] * c[3][i];

    __syncthreads();
    if (t < 64) red[t] = 0.f;
    __syncthreads();
#pragma unroll
    for (int i = 0; i < 8; i++) atomicAdd(&red[8 * q + i], na[i]);
    __syncthreads();
    if (t < 64) atomicAdd(&NA[t], red[t]);
}

constexpr int NBB0 = (100000 + 127) / 128;  // 782
constexpr int NBB1 = (225000 + 127) / 128;  // 1758
constexpr int NBB2 = (175000 + 127) / 128;  // 1368

__global__ __launch_bounds__(256) void kernelB_all(const float* __restrict__ B0,
                                                   const float* __restrict__ B1,
                                                   const float* __restrict__ B2,
                                                   const float* __restrict__ E,
                                                   float* __restrict__ NA) {
    __shared__ __align__(16) float Bs[128 * 52];
    __shared__ float red[64];
    const int bx = blockIdx.x;
    if (bx < NBB0) {
        kernelB_body<104>(B0, E, 100000, 0,   bx,               Bs, red, NA);
    } else if (bx < NBB0 + NBB1) {
        kernelB_body<156>(B1, E, 225000, 104, bx - NBB0,        Bs, red, NA);
    } else {
        kernelB_body<138>(B2, E, 175000, 260, bx - NBB0 - NBB1, Bs, red, NA);
    }
}

// ---------------- Kernel C: scales, out0 (avg clipped embedding), w ----------------
__global__ __launch_bounds__(256) void kernelC(const float* __restrict__ NG,
                                               const float* __restrict__ NA,
                                               const float* __restrict__ E,
                                               float* __restrict__ w, float* __restrict__ sRes,
                                               float* __restrict__ out0) {
    __shared__ float red[256];
    __shared__ float sEmb[64], sResS[64];
    const int t = threadIdx.x;
    const int b = t & 63, part = t >> 6;

    float acc = 0.f;
    for (int k = part * 100; k < part * 100 + 100; k++) {  // pad cols 398/399 are 0
        float v = E[b * KTP_ + k];
        acc += v * v;
    }
    red[part * 64 + b] = acc;
    __syncthreads();
    if (t < 64) {
        float ne   = red[t] + red[64 + t] + red[128 + t] + red[192 + t];
        float nrm  = sqrtf(fmaxf(ne, 0.f));
        sEmb[t]    = fminf(1.0f / nrm, 1.0f);   // CLIP0 = 1
        // <G[b], approx[b]> == ||E[b]||^2 exactly (E = G B):
        float rn2  = NG[t] - 2.f * ne + NA[t];
        float rnrm = sqrtf(fmaxf(rn2, 0.f));
        float sv   = fminf(1.0f / rnrm, 1.0f);  // CLIP1 = 1
        sResS[t]   = sv;
        sRes[t]    = sv;
    }
    __syncthreads();

    for (int k = t; k < KT_; k += 256) {
        float e0 = 0.f, wv = 0.f;
        for (int bb = 0; bb < 64; bb++) {
            float v = E[bb * KTP_ + k];
            e0 += sEmb[bb] * v;
            wv += sResS[bb] * v;
        }
        out0[k] = e0 * (1.f / 64.f);
        w[k]    = wv;
    }
}

// ---------------- Pass D: out1 = (sum_b s_b G[b,p] - w . B[p,:]) / 64 ; out2 = mean_b G ----------------
// v2: no B LDS tile (B reuse = 1 -> stream per-thread rows). One p per thread, 256 p per block.
template <int KG>
__device__ __forceinline__ void kernelD_body(const float* __restrict__ G,
                                             const float* __restrict__ Bg,
                                             const float* __restrict__ w,
                                             const float* __restrict__ sRes,
                                             int Pg, int poff, int koff,
                                             float* __restrict__ out1, float* __restrict__ out2,
                                             int bid, float* __restrict__ wS,
                                             float* __restrict__ sS) {
    const int t = threadIdx.x;
    for (int k = t; k < KG; k += 256) wS[k] = w[koff + k];
    if (t < 64) sS[t] = sRes[t];
    __syncthreads();

    const int p = bid * 256 + t;
    if (p >= Pg) return;

    const float* gp = G + poff + p;
    float a = 0.f, t2 = 0.f;
#pragma unroll 16
    for (int b = 0; b < 64; b++) {
        float g = gp[(size_t)b * PT_];   // coalesced across the block
        a  += sS[b] * g;                 // LDS broadcast
        t2 += g;
    }

    const float* Brow = Bg + (size_t)p * KG;
    float dot = 0.f;
    if constexpr ((KG % 4) == 0) {       // 16B-aligned rows (KG=104,156)
        for (int k = 0; k < KG; k += 4) {
            float4 bv = *reinterpret_cast<const float4*>(&Brow[k]);
            float4 wv = *reinterpret_cast<const float4*>(&wS[k]);
            dot += bv.x * wv.x + bv.y * wv.y + bv.z * wv.z + bv.w * wv.w;
        }
    } else {                             // KG=138: 8B-aligned rows
        for (int k = 0; k < KG; k += 2) {
            float2 bv = *reinterpret_cast<const float2*>(&Brow[k]);
            float2 wv = *reinterpret_cast<const float2*>(&wS[k]);
            dot += bv.x * wv.x + bv.y * wv.y;
        }
    }

    out1[poff + p] = (a - dot) * (1.f / 64.f);
    out2[poff + p] = t2 * (1.f / 64.f);
}

constexpr int NBD0 = (100000 + 255) / 256;  // 391
constexpr int NBD1 = (225000 + 255) / 256;  // 879
constexpr int NBD2 = (175000 + 255) / 256;  // 684

__global__ __launch_bounds__(256) void kernelD_all(const float* __restrict__ G,
                                                   const float* __restrict__ B0,
                                                   const float* __restrict__ B1,
                                                   const float* __restrict__ B2,
                                                   const float* __restrict__ w,
                                                   const float* __restrict__ sRes,
                                                   float* __restrict__ out1,
                                                   float* __restrict__ out2) {
    __shared__ __align__(16) float wS[156];
    __shared__ float sS[64];
    const int bx = blockIdx.x;
    if (bx < NBD0) {
        kernelD_body<104>(G, B0, w, sRes, 100000, 0,      0,   out1, out2, bx,               wS, sS);
    } else if (bx < NBD0 + NBD1) {
        kernelD_body<156>(G, B1, w, sRes, 225000, 100000, 104, out1, out2, bx - NBD0,        wS, sS);
    } else {
        kernelD_body<138>(G, B2, w, sRes, 175000, 325000, 260, out1, out2, bx - NBD0 - NBD1, wS, sS);
    }
}

extern "C" void kernel_launch(void* const* d_in, const int* in_sizes, int n_in,
                              void* d_out, int out_size, void* d_ws, size_t ws_size,
                              hipStream_t stream) {
    const float* G  = (const float*)d_in[0];
    const float* B0 = (const float*)d_in[1];
    const float* B1 = (const float*)d_in[2];
    const float* B2 = (const float*)d_in[3];
    float* out  = (float*)d_out;
    float* out0 = out;                  // [398]
    float* out1 = out + KT_;            // [500000]
    float* out2 = out + KT_ + PT_;      // [500000]

    float* ws = (float*)d_ws;
    float* E  = ws;                     // 25600
    float* NG = ws + 25600;             // 64
    float* NA = NG + 64;                // 64
    float* w  = NA + 64;                // 398
    float* sR = w + KT_;                // 64

    // zero E + NG + NA (ws is poisoned 0xAA before every timed launch)
    zero_kernel<<<101, 256, 0, stream>>>(E, 25728);

    // Pass A (merged, LDS=8.7 KB): embeddings + ||G[b]||^2
    kernelA_all<<<NBA0 + NBA1 + NBA2, 256, 0, stream>>>(G, B0, B1, B2, E, NG);

    // Pass B (merged, chunked-k, LDS=26.9 KB): ||approx[b]||^2
    kernelB_all<<<NBB0 + NBB1 + NBB2, 256, 0, stream>>>(B0, B1, B2, E, NA);

    // Pass C: scales + avg clipped embedding + w
    kernelC<<<1, 256, 0, stream>>>(NG, NA, E, w, sR, out0);

    // Pass D (merged, no B staging): avg clipped residual + avg target grad
    kernelD_all<<<NBD0 + NBD1 + NBD2, 256, 0, stream>>>(G, B0, B1, B2, w, sR, out1, out2);
}

// Round 4
// 797.182 us; speedup vs baseline: 2.1010x; 1.4673x over previous
//
#include <hip/hip_runtime.h>

typedef __attribute__((ext_vector_type(8))) short s8b;   // 8 bf16 bit-patterns (4 VGPR)
typedef __attribute__((ext_vector_type(4))) float f4;    // MFMA accumulator

// Problem constants (from reference)
constexpr int PT_  = 500000;  // total params
constexpr int KT_  = 398;     // total bases
constexpr int KTP_ = 400;     // padded E row stride

// ws layout (floats): E[64*400]@0, NG[64]@25600, NA[64]@25664, w[398]@25728, sRes[64]@26126

__global__ __launch_bounds__(256) void zero_kernel(float* __restrict__ p, int n) {
    int i = blockIdx.x * 256 + threadIdx.x;
    if (i < n) p[i] = 0.f;
}

__device__ __forceinline__ f4 mfma16(s8b a, s8b b, f4 c) {
    return __builtin_amdgcn_mfma_f32_16x16x32_bf16(a, b, c, 0, 0, 0);
}

// x = hi + lo + O(2^-17 x): hi = rne_bf16(x), lo = rne_bf16(x - hi)
__device__ __forceinline__ void split2(float x, short& h, short& l) {
    unsigned u  = __float_as_uint(x);
    unsigned r  = u + 0x7FFFu + ((u >> 16) & 1u);
    float xhi   = __uint_as_float(r & 0xFFFF0000u);
    float lf    = x - xhi;
    unsigned u2 = __float_as_uint(lf);
    unsigned r2 = u2 + 0x7FFFu + ((u2 >> 16) & 1u);
    h = (short)(r >> 16);
    l = (short)(r2 >> 16);
}

__device__ __forceinline__ unsigned packSplit(float x) {  // (hi<<16)|lo
    unsigned u  = __float_as_uint(x);
    unsigned r  = u + 0x7FFFu + ((u >> 16) & 1u);
    unsigned hi = r & 0xFFFF0000u;
    float lf    = x - __uint_as_float(hi);
    unsigned u2 = __float_as_uint(lf);
    unsigned r2 = u2 + 0x7FFFu + ((u2 >> 16) & 1u);
    return hi | (r2 >> 16);
}

// ---------------- Pass A (MFMA): E = G @ B via bf16 hi/lo split + ||G[b]||^2 ----------------
// Per 32-p chunk: stage B packed (hi|lo) transposed [n][p] in LDS (word stride 36 -> 16B-aligned
// b128 frag reads); G loaded straight into A-fragments. Wave w = M-tile rows 16w..16w+15.
template <int KG, int NT, int CP>
__device__ __forceinline__ void passA_body(const float* __restrict__ G,
                                           const float* __restrict__ Bg,
                                           int Pg, int poff, int koff,
                                           float* __restrict__ E,
                                           float* __restrict__ NG,
                                           int bid, unsigned* __restrict__ Bs) {
    constexpr int KP = 16 * NT;
    const int t  = threadIdx.x;
    const int w  = t >> 6;    // wave = M-tile
    const int l  = t & 63;
    const int lr = l & 15;    // operand-major lane index (row of A / col of B)
    const int lg = l >> 4;    // k-group

    // zero pad columns n in [KG, KP) once (never overwritten)
    for (int idx = t; idx < (KP - KG) * 36; idx += 256) Bs[KG * 36 + idx] = 0u;

    f4 acc[NT];
#pragma unroll
    for (int nt = 0; nt < NT; nt++) { acc[nt][0] = 0.f; acc[nt][1] = 0.f; acc[nt][2] = 0.f; acc[nt][3] = 0.f; }

    float ng = 0.f;
    const int p0b = bid * CP;
    const float* __restrict__ gp0 = G + (size_t)(16 * w + lr) * PT_ + poff;

    for (int pc = 0; pc < CP; pc += 32) {
        const int p0 = p0b + pc;
        __syncthreads();
        // stage B[p0..p0+31, :KG): packed hi|lo, transposed [n][p]
        for (int idx = t; idx < 16 * KG; idx += 256) {
            int p = idx & 31;
            int n = (idx >> 5) * 2;
            float2 v;
            if (p0 + p < Pg) v = *reinterpret_cast<const float2*>(&Bg[(size_t)(p0 + p) * KG + n]);
            else { v.x = 0.f; v.y = 0.f; }
            Bs[n * 36 + p]       = packSplit(v.x);
            Bs[(n + 1) * 36 + p] = packSplit(v.y);
        }
        // A-fragment from G: row 16w+lr, k-slots p0 + 8*lg + e
        s8b ahi, alo;
        const float* gp = gp0 + p0 + 8 * lg;
        if (p0 + 32 <= Pg) {
            float4 f0 = *reinterpret_cast<const float4*>(gp);
            float4 f1 = *reinterpret_cast<const float4*>(gp + 4);
            float xs[8] = {f0.x, f0.y, f0.z, f0.w, f1.x, f1.y, f1.z, f1.w};
#pragma unroll
            for (int e = 0; e < 8; e++) {
                short h, lo; split2(xs[e], h, lo);
                ahi[e] = h; alo[e] = lo; ng += xs[e] * xs[e];
            }
        } else {
#pragma unroll
            for (int e = 0; e < 8; e++) {
                float x = (p0 + 8 * lg + e < Pg) ? gp[e] : 0.f;
                short h, lo; split2(x, h, lo);
                ahi[e] = h; alo[e] = lo; ng += x * x;
            }
        }
        __syncthreads();
#pragma unroll
        for (int nt = 0; nt < NT; nt++) {
            const unsigned* bp = &Bs[(nt * 16 + lr) * 36 + 8 * lg];
            uint4 w0 = *reinterpret_cast<const uint4*>(bp);
            uint4 w1 = *reinterpret_cast<const uint4*>(bp + 4);
            unsigned ww[8] = {w0.x, w0.y, w0.z, w0.w, w1.x, w1.y, w1.z, w1.w};
            s8b bhi, blo;
#pragma unroll
            for (int e = 0; e < 8; e++) {
                bhi[e] = (short)(ww[e] >> 16);
                blo[e] = (short)(ww[e] & 0xFFFFu);
            }
            acc[nt] = mfma16(ahi, bhi, acc[nt]);
            acc[nt] = mfma16(ahi, blo, acc[nt]);
            acc[nt] = mfma16(alo, bhi, acc[nt]);
        }
    }

    // E atomics: D layout (m89): col = lr, row = 4*lg + r
#pragma unroll
    for (int nt = 0; nt < NT; nt++) {
        int n = nt * 16 + lr;
        if (n < KG) {
#pragma unroll
            for (int r = 0; r < 4; r++)
                atomicAdd(&E[(16 * w + 4 * lg + r) * KTP_ + koff + n], acc[nt][r]);
        }
    }
    // NG: fold the 4 k-group copies of each row
    ng += __shfl_xor(ng, 16);
    ng += __shfl_xor(ng, 32);
    if (l < 16) atomicAdd(&NG[16 * w + l], ng);
}

constexpr int CPA  = 512;
constexpr int NBA0 = (100000 + CPA - 1) / CPA;  // 196
constexpr int NBA1 = (225000 + CPA - 1) / CPA;  // 440
constexpr int NBA2 = (175000 + CPA - 1) / CPA;  // 342

__global__ __launch_bounds__(256) void kernelA_all(const float* __restrict__ G,
                                                   const float* __restrict__ B0,
                                                   const float* __restrict__ B1,
                                                   const float* __restrict__ B2,
                                                   float* __restrict__ E,
                                                   float* __restrict__ NG) {
    __shared__ unsigned Bs[160 * 36];   // 23040 B (max group: KP=160)
    const int bx = blockIdx.x;
    if (bx < NBA0) {
        passA_body<104, 7, CPA>(G, B0, 100000, 0,      0,   E, NG, bx, Bs);
    } else if (bx < NBA0 + NBA1) {
        passA_body<156, 10, CPA>(G, B1, 225000, 100000, 104, E, NG, bx - NBA0, Bs);
    } else {
        passA_body<138, 9, CPA>(G, B2, 175000, 325000, 260, E, NG, bx - NBA0 - NBA1, Bs);
    }
}

// ---------------- Pass B (MFMA): NA_b = ||E_b @ B^T||^2, B streamed once from global ----------------
// A-op = E (loaded once per block, k-guarded -> zero slots kill B garbage), B-op frag from global
// rows (coalesced 16-row reads). Tile loop is a RUNTIME loop (unroll 1) to cap code size.
template <int KG, int NKB, bool V4>
__device__ __forceinline__ void passB_body(const float* __restrict__ Bg,
                                           const float* __restrict__ E,
                                           int Pg, int koff, int nTiles, int tile0,
                                           float* __restrict__ NA) {
    const int t  = threadIdx.x;
    const int w  = t >> 6;
    const int l  = t & 63;
    const int lr = l & 15, lg = l >> 4;

    s8b ahi[NKB], alo[NKB];
    const float* __restrict__ Erow = E + (16 * w + lr) * KTP_ + koff;
#pragma unroll
    for (int kb = 0; kb < NKB; kb++) {
#pragma unroll
        for (int e = 0; e < 8; e++) {
            int k = kb * 32 + 8 * lg + e;
            float x = (k < KG) ? Erow[k] : 0.f;
            short h, lo; split2(x, h, lo);
            ahi[kb][e] = h; alo[kb][e] = lo;
        }
    }

    float nacc[4] = {0.f, 0.f, 0.f, 0.f};

#pragma unroll 1
    for (int i = 0; i < 4; i++) {
        const int T = tile0 + w + 4 * i;
        if (T >= nTiles) continue;
        f4 acc; acc[0] = 0.f; acc[1] = 0.f; acc[2] = 0.f; acc[3] = 0.f;
        if (T < nTiles - 1) {   // interior: k-overread spills into next row (in-bounds, A=0 there)
            const float* __restrict__ Brow = Bg + (size_t)(16 * T + lr) * KG + 8 * lg;
#pragma unroll
            for (int kb = 0; kb < NKB; kb++) {
                float xs[8];
                if constexpr (V4) {
                    float4 f0 = *reinterpret_cast<const float4*>(Brow + kb * 32);
                    float4 f1 = *reinterpret_cast<const float4*>(Brow + kb * 32 + 4);
                    xs[0] = f0.x; xs[1] = f0.y; xs[2] = f0.z; xs[3] = f0.w;
                    xs[4] = f1.x; xs[5] = f1.y; xs[6] = f1.z; xs[7] = f1.w;
                } else {        // KG=138: rows only 8B-aligned
                    float2 f0 = *reinterpret_cast<const float2*>(Brow + kb * 32);
                    float2 f1 = *reinterpret_cast<const float2*>(Brow + kb * 32 + 2);
                    float2 f2 = *reinterpret_cast<const float2*>(Brow + kb * 32 + 4);
                    float2 f3 = *reinterpret_cast<const float2*>(Brow + kb * 32 + 6);
                    xs[0] = f0.x; xs[1] = f0.y; xs[2] = f1.x; xs[3] = f1.y;
                    xs[4] = f2.x; xs[5] = f2.y; xs[6] = f3.x; xs[7] = f3.y;
                }
                s8b bhi, blo;
#pragma unroll
                for (int e = 0; e < 8; e++) {
                    short h, lo; split2(xs[e], h, lo);
                    bhi[e] = h; blo[e] = lo;
                }
                acc = mfma16(ahi[kb], bhi, acc);
                acc = mfma16(ahi[kb], blo, acc);
                acc = mfma16(alo[kb], bhi, acc);
            }
        } else {                // last tile: row + k fully guarded
            const int prow = 16 * T + lr;
            const float* __restrict__ Brow = Bg + (size_t)prow * KG;
#pragma unroll
            for (int kb = 0; kb < NKB; kb++) {
                s8b bhi, blo;
#pragma unroll
                for (int e = 0; e < 8; e++) {
                    int k = kb * 32 + 8 * lg + e;
                    float x = (prow < Pg && k < KG) ? Brow[k] : 0.f;
                    short h, lo; split2(x, h, lo);
                    bhi[e] = h; blo[e] = lo;
                }
                acc = mfma16(ahi[kb], bhi, acc);
                acc = mfma16(ahi[kb], blo, acc);
                acc = mfma16(alo[kb], bhi, acc);
            }
        }
#pragma unroll
        for (int r = 0; r < 4; r++) nacc[r] += acc[r] * acc[r];
    }

#pragma unroll
    for (int r = 0; r < 4; r++) {   // fold over the 16 p-columns (same b)
        float v = nacc[r];
        v += __shfl_xor(v, 1);
        v += __shfl_xor(v, 2);
        v += __shfl_xor(v, 4);
        v += __shfl_xor(v, 8);
        if (lr == 0) atomicAdd(&NA[16 * w + 4 * lg + r], v);
    }
}

constexpr int TB0  = (100000 + 15) / 16;  // 6250
constexpr int TB1  = (225000 + 15) / 16;  // 14063
constexpr int TB2  = (175000 + 15) / 16;  // 10938
constexpr int NBB0 = (TB0 + 15) / 16;     // 391
constexpr int NBB1 = (TB1 + 15) / 16;     // 879
constexpr int NBB2 = (TB2 + 15) / 16;     // 684

__global__ __launch_bounds__(256) void kernelB_all(const float* __restrict__ B0,
                                                   const float* __restrict__ B1,
                                                   const float* __restrict__ B2,
                                                   const float* __restrict__ E,
                                                   float* __restrict__ NA) {
    const int bx = blockIdx.x;
    if (bx < NBB0)             passB_body<104, 4, true >(B0, E, 100000, 0,   TB0, bx * 16, NA);
    else if (bx < NBB0 + NBB1) passB_body<156, 5, true >(B1, E, 225000, 104, TB1, (bx - NBB0) * 16, NA);
    else                       passB_body<138, 5, false>(B2, E, 175000, 260, TB2, (bx - NBB0 - NBB1) * 16, NA);
}

// ---------------- Kernel C: scales, out0 (avg clipped embedding), w ----------------
__global__ __launch_bounds__(256) void kernelC(const float* __restrict__ NG,
                                               const float* __restrict__ NA,
                                               const float* __restrict__ E,
                                               float* __restrict__ w, float* __restrict__ sRes,
                                               float* __restrict__ out0) {
    __shared__ float red[256];
    __shared__ float sEmb[64], sResS[64];
    const int t = threadIdx.x;
    const int b = t & 63, part = t >> 6;

    float acc = 0.f;
    for (int k = part * 100; k < part * 100 + 100; k++) {  // pad cols 398/399 are 0
        float v = E[b * KTP_ + k];
        acc += v * v;
    }
    red[part * 64 + b] = acc;
    __syncthreads();
    if (t < 64) {
        float ne   = red[t] + red[64 + t] + red[128 + t] + red[192 + t];
        float nrm  = sqrtf(fmaxf(ne, 0.f));
        sEmb[t]    = fminf(1.0f / nrm, 1.0f);   // CLIP0 = 1
        // <G[b], approx[b]> == ||E[b]||^2 (E = G B):
        float rn2  = NG[t] - 2.f * ne + NA[t];
        float rnrm = sqrtf(fmaxf(rn2, 0.f));
        float sv   = fminf(1.0f / rnrm, 1.0f);  // CLIP1 = 1
        sResS[t]   = sv;
        sRes[t]    = sv;
    }
    __syncthreads();

    for (int k = t; k < KT_; k += 256) {
        float e0 = 0.f, wv = 0.f;
        for (int bb = 0; bb < 64; bb++) {
            float v = E[bb * KTP_ + k];
            e0 += sEmb[bb] * v;
            wv += sResS[bb] * v;
        }
        out0[k] = e0 * (1.f / 64.f);
        w[k]    = wv;
    }
}

// ---------------- Pass D: out1 = (sum_b s_b G[b,p] - w . B[p,:]) / 64 ; out2 = mean_b G ----------------
template <int KG>
__device__ __forceinline__ void kernelD_body(const float* __restrict__ G,
                                             const float* __restrict__ Bg,
                                             const float* __restrict__ w,
                                             const float* __restrict__ sRes,
                                             int Pg, int poff, int koff,
                                             float* __restrict__ out1, float* __restrict__ out2,
                                             int bid, float* __restrict__ wS,
                                             float* __restrict__ sS) {
    const int t = threadIdx.x;
    for (int k = t; k < KG; k += 256) wS[k] = w[koff + k];
    if (t < 64) sS[t] = sRes[t];
    __syncthreads();

    const int p = bid * 256 + t;
    if (p >= Pg) return;

    const float* gp = G + poff + p;
    float a = 0.f, t2 = 0.f;
#pragma unroll 16
    for (int b = 0; b < 64; b++) {
        float g = gp[(size_t)b * PT_];
        a  += sS[b] * g;
        t2 += g;
    }

    const float* Brow = Bg + (size_t)p * KG;
    float dot = 0.f;
    if constexpr ((KG % 4) == 0) {
        for (int k = 0; k < KG; k += 4) {
            float4 bv = *reinterpret_cast<const float4*>(&Brow[k]);
            float4 wv = *reinterpret_cast<const float4*>(&wS[k]);
            dot += bv.x * wv.x + bv.y * wv.y + bv.z * wv.z + bv.w * wv.w;
        }
    } else {
        for (int k = 0; k < KG; k += 2) {
            float2 bv = *reinterpret_cast<const float2*>(&Brow[k]);
            float2 wv = *reinterpret_cast<const float2*>(&wS[k]);
            dot += bv.x * wv.x + bv.y * wv.y;
        }
    }

    out1[poff + p] = (a - dot) * (1.f / 64.f);
    out2[poff + p] = t2 * (1.f / 64.f);
}

constexpr int NBD0 = (100000 + 255) / 256;  // 391
constexpr int NBD1 = (225000 + 255) / 256;  // 879
constexpr int NBD2 = (175000 + 255) / 256;  // 684

__global__ __launch_bounds__(256) void kernelD_all(const float* __restrict__ G,
                                                   const float* __restrict__ B0,
                                                   const float* __restrict__ B1,
                                                   const float* __restrict__ B2,
                                                   const float* __restrict__ w,
                                                   const float* __restrict__ sRes,
                                                   float* __restrict__ out1,
                                                   float* __restrict__ out2) {
    __shared__ __align__(16) float wS[156];
    __shared__ float sS[64];
    const int bx = blockIdx.x;
    if (bx < NBD0) {
        kernelD_body<104>(G, B0, w, sRes, 100000, 0,      0,   out1, out2, bx,               wS, sS);
    } else if (bx < NBD0 + NBD1) {
        kernelD_body<156>(G, B1, w, sRes, 225000, 100000, 104, out1, out2, bx - NBD0,        wS, sS);
    } else {
        kernelD_body<138>(G, B2, w, sRes, 175000, 325000, 260, out1, out2, bx - NBD0 - NBD1, wS, sS);
    }
}

extern "C" void kernel_launch(void* const* d_in, const int* in_sizes, int n_in,
                              void* d_out, int out_size, void* d_ws, size_t ws_size,
                              hipStream_t stream) {
    const float* G  = (const float*)d_in[0];
    const float* B0 = (const float*)d_in[1];
    const float* B1 = (const float*)d_in[2];
    const float* B2 = (const float*)d_in[3];
    float* out  = (float*)d_out;
    float* out0 = out;                  // [398]
    float* out1 = out + KT_;            // [500000]
    float* out2 = out + KT_ + PT_;      // [500000]

    float* ws = (float*)d_ws;
    float* E  = ws;                     // 25600
    float* NG = ws + 25600;             // 64
    float* NA = NG + 64;                // 64
    float* w  = NA + 64;                // 398
    float* sR = w + KT_;                // 64

    // zero E + NG + NA (ws is poisoned before every timed launch)
    zero_kernel<<<101, 256, 0, stream>>>(E, 25728);

    // Pass A (MFMA bf16-split): embeddings + ||G[b]||^2
    kernelA_all<<<NBA0 + NBA1 + NBA2, 256, 0, stream>>>(G, B0, B1, B2, E, NG);

    // Pass B (MFMA bf16-split, no LDS): ||approx[b]||^2
    kernelB_all<<<NBB0 + NBB1 + NBB2, 256, 0, stream>>>(B0, B1, B2, E, NA);

    // Pass C: scales + avg clipped embedding + w
    kernelC<<<1, 256, 0, stream>>>(NG, NA, E, w, sR, out0);

    // Pass D: avg clipped residual + avg target grad
    kernelD_all<<<NBD0 + NBD1 + NBD2, 256, 0, stream>>>(G, B0, B1, B2, w, sR, out1, out2);
}